// Round 6
// baseline (559.807 us; speedup 1.0000x reference)
//
#include <hip/hip_runtime.h>
#include <hip/hip_cooperative_groups.h>
#include <math.h>

namespace cg = cooperative_groups;

#define DIM 4096
#define INTER 11008
#define EPS 1e-5f
#define THRESH 0.05f

typedef float f4 __attribute__((ext_vector_type(4)));

__device__ __forceinline__ f4 ld4(const float* p) {
    return *reinterpret_cast<const f4*>(p);
}

__device__ __forceinline__ float wave_sum(float v) {
#pragma unroll
    for (int off = 32; off > 0; off >>= 1) v += __shfl_xor(v, off, 64);
    return v;
}

__device__ __forceinline__ float thr(float v) {
    return (fabsf(v) > THRESH) ? v : 0.f;
}

// Per-wave RMS scale of a DIM-length vector (redundant per wave; vector is
// L2-resident so this hides under HBM weight streaming).
__device__ __forceinline__ float wave_rms_scale(const float* __restrict__ x,
                                                int lane) {
    float ss = 0.f;
#pragma unroll
    for (int k = 0; k < DIM; k += 256) {
        f4 v = ld4(x + k + (lane << 2));
        ss = fmaf(v.x, v.x, ss);
        ss = fmaf(v.y, v.y, ss);
        ss = fmaf(v.z, v.z, ss);
        ss = fmaf(v.w, v.w, ss);
    }
    ss = wave_sum(ss);
    return rsqrtf(ss * (1.f / (float)DIM) + EPS);
}

// dot(W[row], thr(x*scale*nw)) over K=DIM (round-2 best structure, cached loads)
__device__ __forceinline__ float dot_row_norm(const float* __restrict__ wr,
        const float* __restrict__ x, const float* __restrict__ nw,
        float scale, int lane) {
    float acc[4] = {0.f, 0.f, 0.f, 0.f};
    for (int k = 0; k < DIM; k += 1024) {
#pragma unroll
        for (int u = 0; u < 4; ++u) {
            const int kk = k + (u << 8) + (lane << 2);
            f4 wv = ld4(wr + kk);
            f4 xv = ld4(x + kk);
            f4 nv = ld4(nw + kk);
            float x0 = thr(xv.x * scale * nv.x);
            float x1 = thr(xv.y * scale * nv.y);
            float x2 = thr(xv.z * scale * nv.z);
            float x3 = thr(xv.w * scale * nv.w);
            acc[u] = fmaf(wv.x, x0, acc[u]);
            acc[u] = fmaf(wv.y, x1, acc[u]);
            acc[u] = fmaf(wv.z, x2, acc[u]);
            acc[u] = fmaf(wv.w, x3, acc[u]);
        }
    }
    return wave_sum((acc[0] + acc[1]) + (acc[2] + acc[3]));
}

// plain dot(W[row], x) over K=DIM
__device__ __forceinline__ float dot_row(const float* __restrict__ wr,
        const float* __restrict__ x, int lane) {
    float acc[4] = {0.f, 0.f, 0.f, 0.f};
    for (int k = 0; k < DIM; k += 1024) {
#pragma unroll
        for (int u = 0; u < 4; ++u) {
            const int kk = k + (u << 8) + (lane << 2);
            f4 wv = ld4(wr + kk);
            f4 xv = ld4(x + kk);
            acc[u] = fmaf(wv.x, xv.x, acc[u]);
            acc[u] = fmaf(wv.y, xv.y, acc[u]);
            acc[u] = fmaf(wv.z, xv.z, acc[u]);
            acc[u] = fmaf(wv.w, xv.w, acc[u]);
        }
    }
    return wave_sum((acc[0] + acc[1]) + (acc[2] + acc[3]));
}

// simultaneous dots of w1[row],w3[row] against normalized h
__device__ __forceinline__ void dot2_row_norm(const float* __restrict__ w1r,
        const float* __restrict__ w3r, const float* __restrict__ h,
        const float* __restrict__ nw, float scale, int lane,
        float& g_out, float& u_out) {
    float g[2] = {0.f, 0.f}, u[2] = {0.f, 0.f};
    for (int k = 0; k < DIM; k += 512) {
#pragma unroll
        for (int p = 0; p < 2; ++p) {
            const int kk = k + (p << 8) + (lane << 2);
            f4 hv = ld4(h + kk);
            f4 nv = ld4(nw + kk);
            f4 av = ld4(w1r + kk);
            f4 bv = ld4(w3r + kk);
            float x0 = thr(hv.x * scale * nv.x);
            float x1 = thr(hv.y * scale * nv.y);
            float x2 = thr(hv.z * scale * nv.z);
            float x3 = thr(hv.w * scale * nv.w);
            g[p] = fmaf(av.x, x0, g[p]);
            g[p] = fmaf(av.y, x1, g[p]);
            g[p] = fmaf(av.z, x2, g[p]);
            g[p] = fmaf(av.w, x3, g[p]);
            u[p] = fmaf(bv.x, x0, u[p]);
            u[p] = fmaf(bv.y, x1, u[p]);
            u[p] = fmaf(bv.z, x2, u[p]);
            u[p] = fmaf(bv.w, x3, u[p]);
        }
    }
    g_out = wave_sum(g[0] + g[1]);
    u_out = wave_sum(u[0] + u[1]);
}

// dot(W2[row], x) over K=INTER
__device__ __forceinline__ float dot_row_inter(const float* __restrict__ wr,
        const float* __restrict__ x, int lane) {
    float acc[4] = {0.f, 0.f, 0.f, 0.f};
    int k = 0;
    for (; k + 1024 <= INTER; k += 1024) {
#pragma unroll
        for (int u = 0; u < 4; ++u) {
            const int kk = k + (u << 8) + (lane << 2);
            f4 wv = ld4(wr + kk);
            f4 xv = ld4(x + kk);
            acc[u] = fmaf(wv.x, xv.x, acc[u]);
            acc[u] = fmaf(wv.y, xv.y, acc[u]);
            acc[u] = fmaf(wv.z, xv.z, acc[u]);
            acc[u] = fmaf(wv.w, xv.w, acc[u]);
        }
    }
#pragma unroll
    for (int u = 0; u < 3; ++u) {  // tail 768 = 3*256
        const int kk = k + (u << 8) + (lane << 2);
        f4 wv = ld4(wr + kk);
        f4 xv = ld4(x + kk);
        acc[u] = fmaf(wv.x, xv.x, acc[u]);
        acc[u] = fmaf(wv.y, xv.y, acc[u]);
        acc[u] = fmaf(wv.z, xv.z, acc[u]);
        acc[u] = fmaf(wv.w, xv.w, acc[u]);
    }
    return wave_sum((acc[0] + acc[1]) + (acc[2] + acc[3]));
}

__device__ __forceinline__ float silu_mul_thr(float g, float u) {
    float s = g / (1.f + expf(-g));
    return thr(s * u);
}

// ---------------- fused cooperative kernel ----------------
// 1024 blocks x 256 threads = 4096 waves, 4 blocks/CU. Identical per-wave
// structure to the 4-kernel round-2 chain; ONLY change vs round 3 is plain
// cached loads (no nontemporal) — isolates nt as round 3's poison.
__global__ __launch_bounds__(256, 4) void fused_layer_kernel(
        const float* __restrict__ x, const float* __restrict__ wv,
        const float* __restrict__ wo, const float* __restrict__ w1,
        const float* __restrict__ w2, const float* __restrict__ w3,
        const float* __restrict__ anw, const float* __restrict__ fnw,
        float* __restrict__ vt, float* __restrict__ h,
        float* __restrict__ actt, float* __restrict__ out) {
    cg::grid_group grid = cg::this_grid();
    const int lane = threadIdx.x & 63;
    const int wid = (blockIdx.x << 2) + (threadIdx.x >> 6);  // 0..4095

    // Phase 1: vt = thr(wv · thr(rmsnorm(x)*anw))   (SEQ=1: attn out == V)
    {
        const float scale = wave_rms_scale(x, lane);
        float a = dot_row_norm(wv + (size_t)wid * DIM, x, anw, scale, lane);
        if (lane == 0) vt[wid] = thr(a);
    }
    grid.sync();

    // Phase 2: h = x + wo · vt
    {
        float a = dot_row(wo + (size_t)wid * DIM, vt, lane);
        if (lane == 0) h[wid] = x[wid] + a;
    }
    grid.sync();

    // Phase 3: actt[r] = thr(silu(w1·hn) * (w3·hn)), rows wid, wid+4096, wid+8192
    // (strided assignment self-balances to +2.3% per-CU)
    {
        const float scale = wave_rms_scale(h, lane);
        for (int r = wid; r < INTER; r += 4096) {
            float g, u;
            dot2_row_norm(w1 + (size_t)r * DIM, w3 + (size_t)r * DIM,
                          h, fnw, scale, lane, g, u);
            if (lane == 0) actt[r] = silu_mul_thr(g, u);
        }
    }
    grid.sync();

    // Phase 4: out = h + w2 · actt
    {
        float a = dot_row_inter(w2 + (size_t)wid * INTER, actt, lane);
        if (lane == 0) out[wid] = h[wid] + a;
    }
}

// ---------------- fallback kernels (round-2 proven chain) ----------------
__global__ __launch_bounds__(256) void k_v(const float* __restrict__ wv,
        const float* __restrict__ x, const float* __restrict__ anw,
        float* __restrict__ vt) {
    const int lane = threadIdx.x & 63;
    const int wid = (blockIdx.x << 2) + (threadIdx.x >> 6);
    const float scale = wave_rms_scale(x, lane);
    float a = dot_row_norm(wv + (size_t)wid * DIM, x, anw, scale, lane);
    if (lane == 0) vt[wid] = thr(a);
}
__global__ __launch_bounds__(256) void k_o(const float* __restrict__ wo,
        const float* __restrict__ vt, const float* __restrict__ x,
        float* __restrict__ h) {
    const int lane = threadIdx.x & 63;
    const int wid = (blockIdx.x << 2) + (threadIdx.x >> 6);
    float a = dot_row(wo + (size_t)wid * DIM, vt, lane);
    if (lane == 0) h[wid] = x[wid] + a;
}
__global__ __launch_bounds__(256) void k_gu(const float* __restrict__ w1,
        const float* __restrict__ w3, const float* __restrict__ h,
        const float* __restrict__ fnw, float* __restrict__ actt) {
    const int lane = threadIdx.x & 63;
    const int wid = (blockIdx.x << 2) + (threadIdx.x >> 6);
    const float scale = wave_rms_scale(h, lane);
    float g, u;
    dot2_row_norm(w1 + (size_t)wid * DIM, w3 + (size_t)wid * DIM,
                  h, fnw, scale, lane, g, u);
    if (lane == 0) actt[wid] = silu_mul_thr(g, u);
}
__global__ __launch_bounds__(256) void k_d(const float* __restrict__ w2,
        const float* __restrict__ actt, const float* __restrict__ h,
        float* __restrict__ out) {
    const int lane = threadIdx.x & 63;
    const int wid = (blockIdx.x << 2) + (threadIdx.x >> 6);
    float a = dot_row_inter(w2 + (size_t)wid * INTER, actt, lane);
    if (lane == 0) out[wid] = h[wid] + a;
}

extern "C" void kernel_launch(void* const* d_in, const int* in_sizes, int n_in,
                              void* d_out, int out_size, void* d_ws, size_t ws_size,
                              hipStream_t stream) {
    // setup_inputs order: x, freqs_cis, wqkv, wo, w1, w2, w3, attn_norm_w, ffn_norm_w, mask
    const float* x    = (const float*)d_in[0];
    const float* wqkv = (const float*)d_in[2];
    const float* wo   = (const float*)d_in[3];
    const float* w1   = (const float*)d_in[4];
    const float* w2   = (const float*)d_in[5];
    const float* w3   = (const float*)d_in[6];
    const float* anw  = (const float*)d_in[7];
    const float* fnw  = (const float*)d_in[8];
    float* out = (float*)d_out;

    float* ws   = (float*)d_ws;
    float* vt   = ws;            // 4096
    float* h    = ws + 4096;     // 4096
    float* actt = ws + 8192;     // 11008

    // V block of wqkv; Q/K rows are dead at SEQ=1 (softmax over 1 key == 1,
    // RoPE at pos 0 is identity).
    const float* wv = wqkv + (size_t)2 * 4096 * DIM;

    void* args[] = {(void*)&x, (void*)&wv, (void*)&wo, (void*)&w1,
                    (void*)&w2, (void*)&w3, (void*)&anw, (void*)&fnw,
                    (void*)&vt, (void*)&h, (void*)&actt, (void*)&out};
    hipError_t err = hipLaunchCooperativeKernel(
        (const void*)fused_layer_kernel, dim3(1024), dim3(256), args, 0, stream);
    if (err != hipSuccess) {
        // fallback: proven round-2 4-kernel chain
        k_v <<<DIM / 4, 256, 0, stream>>>(wv, x, anw, vt);
        k_o <<<DIM / 4, 256, 0, stream>>>(wo, vt, x, h);
        k_gu<<<INTER / 4, 256, 0, stream>>>(w1, w3, h, fnw, actt);
        k_d <<<DIM / 4, 256, 0, stream>>>(w2, actt, h, out);
    }
}

// Round 7
// 547.589 us; speedup vs baseline: 1.0223x; 1.0223x over previous
//
#include <hip/hip_runtime.h>
#include <math.h>

#define DIM 4096
#define INTER 11008
#define EPS 1e-5f
#define THRESH 0.05f
#define NBLOCKS 1024

typedef float f4 __attribute__((ext_vector_type(4)));

__device__ __forceinline__ f4 ld4(const float* p) {
    return *reinterpret_cast<const f4*>(p);
}

__device__ __forceinline__ float wave_sum(float v) {
#pragma unroll
    for (int off = 32; off > 0; off >>= 1) v += __shfl_xor(v, off, 64);
    return v;
}

__device__ __forceinline__ float thr(float v) {
    return (fabsf(v) > THRESH) ? v : 0.f;
}

// Per-wave RMS scale of a DIM-length vector.
__device__ __forceinline__ float wave_rms_scale(const float* __restrict__ x,
                                                int lane) {
    float ss = 0.f;
#pragma unroll
    for (int k = 0; k < DIM; k += 256) {
        f4 v = ld4(x + k + (lane << 2));
        ss = fmaf(v.x, v.x, ss);
        ss = fmaf(v.y, v.y, ss);
        ss = fmaf(v.z, v.z, ss);
        ss = fmaf(v.w, v.w, ss);
    }
    ss = wave_sum(ss);
    return rsqrtf(ss * (1.f / (float)DIM) + EPS);
}

__device__ __forceinline__ float dot_row_norm(const float* __restrict__ wr,
        const float* __restrict__ x, const float* __restrict__ nw,
        float scale, int lane) {
    float acc[4] = {0.f, 0.f, 0.f, 0.f};
    for (int k = 0; k < DIM; k += 1024) {
#pragma unroll
        for (int u = 0; u < 4; ++u) {
            const int kk = k + (u << 8) + (lane << 2);
            f4 wv = ld4(wr + kk);
            f4 xv = ld4(x + kk);
            f4 nv = ld4(nw + kk);
            float x0 = thr(xv.x * scale * nv.x);
            float x1 = thr(xv.y * scale * nv.y);
            float x2 = thr(xv.z * scale * nv.z);
            float x3 = thr(xv.w * scale * nv.w);
            acc[u] = fmaf(wv.x, x0, acc[u]);
            acc[u] = fmaf(wv.y, x1, acc[u]);
            acc[u] = fmaf(wv.z, x2, acc[u]);
            acc[u] = fmaf(wv.w, x3, acc[u]);
        }
    }
    return wave_sum((acc[0] + acc[1]) + (acc[2] + acc[3]));
}

__device__ __forceinline__ float dot_row(const float* __restrict__ wr,
        const float* __restrict__ x, int lane) {
    float acc[4] = {0.f, 0.f, 0.f, 0.f};
    for (int k = 0; k < DIM; k += 1024) {
#pragma unroll
        for (int u = 0; u < 4; ++u) {
            const int kk = k + (u << 8) + (lane << 2);
            f4 wv = ld4(wr + kk);
            f4 xv = ld4(x + kk);
            acc[u] = fmaf(wv.x, xv.x, acc[u]);
            acc[u] = fmaf(wv.y, xv.y, acc[u]);
            acc[u] = fmaf(wv.z, xv.z, acc[u]);
            acc[u] = fmaf(wv.w, xv.w, acc[u]);
        }
    }
    return wave_sum((acc[0] + acc[1]) + (acc[2] + acc[3]));
}

__device__ __forceinline__ void dot2_row_norm(const float* __restrict__ w1r,
        const float* __restrict__ w3r, const float* __restrict__ h,
        const float* __restrict__ nw, float scale, int lane,
        float& g_out, float& u_out) {
    float g[2] = {0.f, 0.f}, u[2] = {0.f, 0.f};
    for (int k = 0; k < DIM; k += 512) {
#pragma unroll
        for (int p = 0; p < 2; ++p) {
            const int kk = k + (p << 8) + (lane << 2);
            f4 hv = ld4(h + kk);
            f4 nv = ld4(nw + kk);
            f4 av = ld4(w1r + kk);
            f4 bv = ld4(w3r + kk);
            float x0 = thr(hv.x * scale * nv.x);
            float x1 = thr(hv.y * scale * nv.y);
            float x2 = thr(hv.z * scale * nv.z);
            float x3 = thr(hv.w * scale * nv.w);
            g[p] = fmaf(av.x, x0, g[p]);
            g[p] = fmaf(av.y, x1, g[p]);
            g[p] = fmaf(av.z, x2, g[p]);
            g[p] = fmaf(av.w, x3, g[p]);
            u[p] = fmaf(bv.x, x0, u[p]);
            u[p] = fmaf(bv.y, x1, u[p]);
            u[p] = fmaf(bv.z, x2, u[p]);
            u[p] = fmaf(bv.w, x3, u[p]);
        }
    }
    g_out = wave_sum(g[0] + g[1]);
    u_out = wave_sum(u[0] + u[1]);
}

__device__ __forceinline__ float dot_row_inter(const float* __restrict__ wr,
        const float* __restrict__ x, int lane) {
    float acc[4] = {0.f, 0.f, 0.f, 0.f};
    int k = 0;
    for (; k + 1024 <= INTER; k += 1024) {
#pragma unroll
        for (int u = 0; u < 4; ++u) {
            const int kk = k + (u << 8) + (lane << 2);
            f4 wv = ld4(wr + kk);
            f4 xv = ld4(x + kk);
            acc[u] = fmaf(wv.x, xv.x, acc[u]);
            acc[u] = fmaf(wv.y, xv.y, acc[u]);
            acc[u] = fmaf(wv.z, xv.z, acc[u]);
            acc[u] = fmaf(wv.w, xv.w, acc[u]);
        }
    }
#pragma unroll
    for (int u = 0; u < 3; ++u) {  // tail 768 = 3*256
        const int kk = k + (u << 8) + (lane << 2);
        f4 wv = ld4(wr + kk);
        f4 xv = ld4(x + kk);
        acc[u] = fmaf(wv.x, xv.x, acc[u]);
        acc[u] = fmaf(wv.y, xv.y, acc[u]);
        acc[u] = fmaf(wv.z, xv.z, acc[u]);
        acc[u] = fmaf(wv.w, xv.w, acc[u]);
    }
    return wave_sum((acc[0] + acc[1]) + (acc[2] + acc[3]));
}

__device__ __forceinline__ float silu_mul_thr(float g, float u) {
    float s = g / (1.f + expf(-g));
    return thr(s * u);
}

// ---- hand-rolled global barrier ----
// Arrival: one agent-scope RELEASE fetch_add per block (publishes the
// block's phase writes). Spin: RELAXED loads only (no per-poll cache
// invalidate — this is the hypothesized difference vs cg::grid.sync()).
// One ACQUIRE load after the spin establishes ordering.
__device__ __forceinline__ void global_barrier(unsigned int* cnt) {
    __syncthreads();
    if (threadIdx.x == 0) {
        __hip_atomic_fetch_add(cnt, 1u, __ATOMIC_RELEASE,
                               __HIP_MEMORY_SCOPE_AGENT);
        while (__hip_atomic_load(cnt, __ATOMIC_RELAXED,
                                 __HIP_MEMORY_SCOPE_AGENT) < NBLOCKS) {
            __builtin_amdgcn_s_sleep(2);
        }
        (void)__hip_atomic_load(cnt, __ATOMIC_ACQUIRE,
                                __HIP_MEMORY_SCOPE_AGENT);
    }
    __syncthreads();
}

__global__ void init_barriers(unsigned int* cnt) {
    cnt[0] = 0u;
    cnt[1] = 0u;
    cnt[2] = 0u;
}

// ---------------- fused kernel, regular launch ----------------
// 1024 blocks x 256 threads = 4096 waves, 4 blocks/CU (capacity >= 8/CU at
// VGPR~64, LDS=0 -> all co-resident, no deadlock). Identical work partition
// to the round-6 cooperative kernel; ONLY the barrier implementation differs.
__global__ __launch_bounds__(256, 4) void fused_layer_kernel(
        const float* __restrict__ x, const float* __restrict__ wv,
        const float* __restrict__ wo, const float* __restrict__ w1,
        const float* __restrict__ w2, const float* __restrict__ w3,
        const float* __restrict__ anw, const float* __restrict__ fnw,
        float* __restrict__ vt, float* __restrict__ h,
        float* __restrict__ actt, float* __restrict__ out,
        unsigned int* __restrict__ bar) {
    const int lane = threadIdx.x & 63;
    const int wid = (blockIdx.x << 2) + (threadIdx.x >> 6);  // 0..4095

    // Phase 1: vt = thr(wv · thr(rmsnorm(x)*anw))   (SEQ=1: attn out == V)
    {
        const float scale = wave_rms_scale(x, lane);
        float a = dot_row_norm(wv + (size_t)wid * DIM, x, anw, scale, lane);
        if (lane == 0) vt[wid] = thr(a);
    }
    global_barrier(bar + 0);

    // Phase 2: h = x + wo · vt
    {
        float a = dot_row(wo + (size_t)wid * DIM, vt, lane);
        if (lane == 0) h[wid] = x[wid] + a;
    }
    global_barrier(bar + 1);

    // Phase 3: actt[r] = thr(silu(w1·hn)*(w3·hn)), rows wid, wid+4096, wid+8192
    {
        const float scale = wave_rms_scale(h, lane);
        for (int r = wid; r < INTER; r += 4096) {
            float g, u;
            dot2_row_norm(w1 + (size_t)r * DIM, w3 + (size_t)r * DIM,
                          h, fnw, scale, lane, g, u);
            if (lane == 0) actt[r] = silu_mul_thr(g, u);
        }
    }
    global_barrier(bar + 2);

    // Phase 4: out = h + w2 · actt
    {
        float a = dot_row_inter(w2 + (size_t)wid * INTER, actt, lane);
        if (lane == 0) out[wid] = h[wid] + a;
    }
}

extern "C" void kernel_launch(void* const* d_in, const int* in_sizes, int n_in,
                              void* d_out, int out_size, void* d_ws, size_t ws_size,
                              hipStream_t stream) {
    // setup_inputs order: x, freqs_cis, wqkv, wo, w1, w2, w3, attn_norm_w, ffn_norm_w, mask
    const float* x    = (const float*)d_in[0];
    const float* wqkv = (const float*)d_in[2];
    const float* wo   = (const float*)d_in[3];
    const float* w1   = (const float*)d_in[4];
    const float* w2   = (const float*)d_in[5];
    const float* w3   = (const float*)d_in[6];
    const float* anw  = (const float*)d_in[7];
    const float* fnw  = (const float*)d_in[8];
    float* out = (float*)d_out;

    float* ws   = (float*)d_ws;
    float* vt   = ws;            // 4096
    float* h    = ws + 4096;     // 4096
    float* actt = ws + 8192;     // 11008
    unsigned int* bar = (unsigned int*)(ws + 20480);  // 3 counters (64B-aligned)

    // V block of wqkv; Q/K rows are dead at SEQ=1 (softmax over 1 key == 1,
    // RoPE at pos 0 is identity).
    const float* wv = wqkv + (size_t)2 * 4096 * DIM;

    init_barriers<<<1, 1, 0, stream>>>(bar);
    fused_layer_kernel<<<NBLOCKS, 256, 0, stream>>>(
        x, wv, wo, w1, w2, w3, anw, fnw, vt, h, actt, out, bar);
}

// Round 8
// 358.900 us; speedup vs baseline: 1.5598x; 1.5257x over previous
//
#include <hip/hip_runtime.h>
#include <math.h>

#define DIM 4096
#define INTER 11008
#define EPS 1e-5f
#define THRESH 0.05f
#define NBLOCKS 1024

typedef float f4 __attribute__((ext_vector_type(4)));

__device__ __forceinline__ f4 ld4(const float* p) {
    return *reinterpret_cast<const f4*>(p);
}

__device__ __forceinline__ float wave_sum(float v) {
#pragma unroll
    for (int off = 32; off > 0; off >>= 1) v += __shfl_xor(v, off, 64);
    return v;
}

__device__ __forceinline__ float thr(float v) {
    return (fabsf(v) > THRESH) ? v : 0.f;
}

// Per-wave RMS scale of a DIM-length vector.
__device__ __forceinline__ float wave_rms_scale(const float* __restrict__ x,
                                                int lane) {
    float ss = 0.f;
#pragma unroll
    for (int k = 0; k < DIM; k += 256) {
        f4 v = ld4(x + k + (lane << 2));
        ss = fmaf(v.x, v.x, ss);
        ss = fmaf(v.y, v.y, ss);
        ss = fmaf(v.z, v.z, ss);
        ss = fmaf(v.w, v.w, ss);
    }
    ss = wave_sum(ss);
    return rsqrtf(ss * (1.f / (float)DIM) + EPS);
}

__device__ __forceinline__ float dot_row_norm(const float* __restrict__ wr,
        const float* __restrict__ x, const float* __restrict__ nw,
        float scale, int lane) {
    float acc[4] = {0.f, 0.f, 0.f, 0.f};
    for (int k = 0; k < DIM; k += 1024) {
#pragma unroll
        for (int u = 0; u < 4; ++u) {
            const int kk = k + (u << 8) + (lane << 2);
            f4 wv = ld4(wr + kk);
            f4 xv = ld4(x + kk);
            f4 nv = ld4(nw + kk);
            float x0 = thr(xv.x * scale * nv.x);
            float x1 = thr(xv.y * scale * nv.y);
            float x2 = thr(xv.z * scale * nv.z);
            float x3 = thr(xv.w * scale * nv.w);
            acc[u] = fmaf(wv.x, x0, acc[u]);
            acc[u] = fmaf(wv.y, x1, acc[u]);
            acc[u] = fmaf(wv.z, x2, acc[u]);
            acc[u] = fmaf(wv.w, x3, acc[u]);
        }
    }
    return wave_sum((acc[0] + acc[1]) + (acc[2] + acc[3]));
}

__device__ __forceinline__ float dot_row(const float* __restrict__ wr,
        const float* __restrict__ x, int lane) {
    float acc[4] = {0.f, 0.f, 0.f, 0.f};
    for (int k = 0; k < DIM; k += 1024) {
#pragma unroll
        for (int u = 0; u < 4; ++u) {
            const int kk = k + (u << 8) + (lane << 2);
            f4 wv = ld4(wr + kk);
            f4 xv = ld4(x + kk);
            acc[u] = fmaf(wv.x, xv.x, acc[u]);
            acc[u] = fmaf(wv.y, xv.y, acc[u]);
            acc[u] = fmaf(wv.z, xv.z, acc[u]);
            acc[u] = fmaf(wv.w, xv.w, acc[u]);
        }
    }
    return wave_sum((acc[0] + acc[1]) + (acc[2] + acc[3]));
}

__device__ __forceinline__ void dot2_row_norm(const float* __restrict__ w1r,
        const float* __restrict__ w3r, const float* __restrict__ h,
        const float* __restrict__ nw, float scale, int lane,
        float& g_out, float& u_out) {
    float g[2] = {0.f, 0.f}, u[2] = {0.f, 0.f};
    for (int k = 0; k < DIM; k += 512) {
#pragma unroll
        for (int p = 0; p < 2; ++p) {
            const int kk = k + (p << 8) + (lane << 2);
            f4 hv = ld4(h + kk);
            f4 nv = ld4(nw + kk);
            f4 av = ld4(w1r + kk);
            f4 bv = ld4(w3r + kk);
            float x0 = thr(hv.x * scale * nv.x);
            float x1 = thr(hv.y * scale * nv.y);
            float x2 = thr(hv.z * scale * nv.z);
            float x3 = thr(hv.w * scale * nv.w);
            g[p] = fmaf(av.x, x0, g[p]);
            g[p] = fmaf(av.y, x1, g[p]);
            g[p] = fmaf(av.z, x2, g[p]);
            g[p] = fmaf(av.w, x3, g[p]);
            u[p] = fmaf(bv.x, x0, u[p]);
            u[p] = fmaf(bv.y, x1, u[p]);
            u[p] = fmaf(bv.z, x2, u[p]);
            u[p] = fmaf(bv.w, x3, u[p]);
        }
    }
    g_out = wave_sum(g[0] + g[1]);
    u_out = wave_sum(u[0] + u[1]);
}

__device__ __forceinline__ float dot_row_inter(const float* __restrict__ wr,
        const float* __restrict__ x, int lane) {
    float acc[4] = {0.f, 0.f, 0.f, 0.f};
    int k = 0;
    for (; k + 1024 <= INTER; k += 1024) {
#pragma unroll
        for (int u = 0; u < 4; ++u) {
            const int kk = k + (u << 8) + (lane << 2);
            f4 wv = ld4(wr + kk);
            f4 xv = ld4(x + kk);
            acc[u] = fmaf(wv.x, xv.x, acc[u]);
            acc[u] = fmaf(wv.y, xv.y, acc[u]);
            acc[u] = fmaf(wv.z, xv.z, acc[u]);
            acc[u] = fmaf(wv.w, xv.w, acc[u]);
        }
    }
#pragma unroll
    for (int u = 0; u < 3; ++u) {  // tail 768 = 3*256
        const int kk = k + (u << 8) + (lane << 2);
        f4 wv = ld4(wr + kk);
        f4 xv = ld4(x + kk);
        acc[u] = fmaf(wv.x, xv.x, acc[u]);
        acc[u] = fmaf(wv.y, xv.y, acc[u]);
        acc[u] = fmaf(wv.z, xv.z, acc[u]);
        acc[u] = fmaf(wv.w, xv.w, acc[u]);
    }
    return wave_sum((acc[0] + acc[1]) + (acc[2] + acc[3]));
}

__device__ __forceinline__ float silu_mul_thr(float g, float u) {
    float s = g / (1.f + expf(-g));
    return thr(s * u);
}

// ---- combining-tree global barrier (anti poll-storm) ----
// Arrival: 32 group counters, one 64B line each (blocks b>>5 share a group);
// last group arriver bumps root; last root arriver sets release flag.
// All acq_rel RMWs -> transitive happens-before via the release chain.
// Spin: RELAXED flag loads with s_sleep(32) (~0.85us) backoff -> total poll
// traffic ~500K/s vs round 7's ~1G/s single-line storm.
// Barrier region layout (uints): grp[g] at g*16 (g<32), root at 512, flag at 528.
__device__ __forceinline__ void global_barrier(unsigned int* bar_region) {
    __syncthreads();
    if (threadIdx.x == 0) {
        unsigned int* grp  = bar_region + ((blockIdx.x >> 5) << 4);
        unsigned int* root = bar_region + 512;
        unsigned int* flag = bar_region + 528;
        unsigned int old = __hip_atomic_fetch_add(grp, 1u, __ATOMIC_ACQ_REL,
                                                  __HIP_MEMORY_SCOPE_AGENT);
        if (old == 31u) {
            unsigned int r = __hip_atomic_fetch_add(root, 1u, __ATOMIC_ACQ_REL,
                                                    __HIP_MEMORY_SCOPE_AGENT);
            if (r == 31u)
                __hip_atomic_store(flag, 1u, __ATOMIC_RELEASE,
                                   __HIP_MEMORY_SCOPE_AGENT);
        }
        while (__hip_atomic_load(flag, __ATOMIC_RELAXED,
                                 __HIP_MEMORY_SCOPE_AGENT) == 0u) {
            __builtin_amdgcn_s_sleep(32);
        }
        (void)__hip_atomic_load(flag, __ATOMIC_ACQUIRE,
                                __HIP_MEMORY_SCOPE_AGENT);
    }
    __syncthreads();
}

// zero all 3 barrier regions (3 x 1024 uints) each launch (ws poisoned 0xAA;
// no state may persist across calls)
__global__ void init_barriers(unsigned int* bar) {
    for (int i = threadIdx.x; i < 3072; i += 256) bar[i] = 0u;
}

// ---------------- fused kernel, regular launch ----------------
// Identical work partition to rounds 6/7; ONLY barrier internals differ.
__global__ __launch_bounds__(256, 4) void fused_layer_kernel(
        const float* __restrict__ x, const float* __restrict__ wv,
        const float* __restrict__ wo, const float* __restrict__ w1,
        const float* __restrict__ w2, const float* __restrict__ w3,
        const float* __restrict__ anw, const float* __restrict__ fnw,
        float* __restrict__ vt, float* __restrict__ h,
        float* __restrict__ actt, float* __restrict__ out,
        unsigned int* __restrict__ bar) {
    const int lane = threadIdx.x & 63;
    const int wid = (blockIdx.x << 2) + (threadIdx.x >> 6);  // 0..4095

    // Phase 1: vt = thr(wv · thr(rmsnorm(x)*anw))   (SEQ=1: attn out == V)
    {
        const float scale = wave_rms_scale(x, lane);
        float a = dot_row_norm(wv + (size_t)wid * DIM, x, anw, scale, lane);
        if (lane == 0) vt[wid] = thr(a);
    }
    global_barrier(bar);

    // Phase 2: h = x + wo · vt
    {
        float a = dot_row(wo + (size_t)wid * DIM, vt, lane);
        if (lane == 0) h[wid] = x[wid] + a;
    }
    global_barrier(bar + 1024);

    // Phase 3: actt[r] = thr(silu(w1·hn)*(w3·hn)), rows wid, wid+4096, wid+8192
    {
        const float scale = wave_rms_scale(h, lane);
        for (int r = wid; r < INTER; r += 4096) {
            float g, u;
            dot2_row_norm(w1 + (size_t)r * DIM, w3 + (size_t)r * DIM,
                          h, fnw, scale, lane, g, u);
            if (lane == 0) actt[r] = silu_mul_thr(g, u);
        }
    }
    global_barrier(bar + 2048);

    // Phase 4: out = h + w2 · actt
    {
        float a = dot_row_inter(w2 + (size_t)wid * INTER, actt, lane);
        if (lane == 0) out[wid] = h[wid] + a;
    }
}

extern "C" void kernel_launch(void* const* d_in, const int* in_sizes, int n_in,
                              void* d_out, int out_size, void* d_ws, size_t ws_size,
                              hipStream_t stream) {
    // setup_inputs order: x, freqs_cis, wqkv, wo, w1, w2, w3, attn_norm_w, ffn_norm_w, mask
    const float* x    = (const float*)d_in[0];
    const float* wqkv = (const float*)d_in[2];
    const float* wo   = (const float*)d_in[3];
    const float* w1   = (const float*)d_in[4];
    const float* w2   = (const float*)d_in[5];
    const float* w3   = (const float*)d_in[6];
    const float* anw  = (const float*)d_in[7];
    const float* fnw  = (const float*)d_in[8];
    float* out = (float*)d_out;

    float* ws   = (float*)d_ws;
    float* vt   = ws;            // 4096
    float* h    = ws + 4096;     // 4096
    float* actt = ws + 8192;     // 11008
    unsigned int* bar = (unsigned int*)(ws + 20480);  // 3 x 1024 uints

    // V block of wqkv; Q/K rows are dead at SEQ=1 (softmax over 1 key == 1,
    // RoPE at pos 0 is identity).
    const float* wv = wqkv + (size_t)2 * 4096 * DIM;

    init_barriers<<<1, 256, 0, stream>>>(bar);
    fused_layer_kernel<<<NBLOCKS, 256, 0, stream>>>(
        x, wv, wo, w1, w2, w3, anw, fnw, vt, h, actt, out, bar);
}